// Round 7
// baseline (607.546 us; speedup 1.0000x reference)
//
#include <hip/hip_runtime.h>

typedef unsigned short ushort_t;
typedef __attribute__((ext_vector_type(8))) short short8;
typedef __attribute__((ext_vector_type(4))) float f32x4;

#define TOKENS  4096
#define H_DIM   1024
#define HFF_DIM 4096
#define NEXP    8

// round-to-nearest-even f32 -> bf16
__device__ __forceinline__ ushort_t f2b(float f) {
    union { float f; unsigned u; } v; v.f = f;
    unsigned r = v.u + 0x7fffu + ((v.u >> 16) & 1u);
    return (ushort_t)(r >> 16);
}

// jax.nn.gelu default: approximate=True (tanh form)
__device__ __forceinline__ float gelu_tanh(float x) {
    float u = 0.7978845608028654f * (x + 0.044715f * x * x * x);
    return 0.5f * x * (1.0f + tanhf(u));
}

// async global->LDS, 16B per lane; LDS dest is wave-uniform base + lane*16
__device__ __forceinline__ void gload16(const ushort_t* g, ushort_t* l) {
    __builtin_amdgcn_global_load_lds(
        (const __attribute__((address_space(1))) unsigned int*)g,
        (__attribute__((address_space(3))) unsigned int*)l,
        16, 0, 0);
}

// ---------------- routing ----------------
__global__ void route_kernel(const float* __restrict__ probs,
                             const int* __restrict__ idx,
                             int* __restrict__ count,
                             int* __restrict__ token_id,
                             float* __restrict__ gate) {
    int t = blockIdx.x * blockDim.x + threadIdx.x;
    if (t >= TOKENS) return;
    int i0 = idx[t * 2 + 0];
    int i1 = idx[t * 2 + 1];
    float p0 = probs[t * 2 + 0];
    float p1 = probs[t * 2 + 1];
    if (i0 == i1) {
        float p = fmaxf(p0, p1);
        int pos = atomicAdd(&count[i0], 1);
        token_id[i0 * TOKENS + pos] = t;
        gate[i0 * TOKENS + pos] = p;
    } else {
        int pos = atomicAdd(&count[i0], 1);
        token_id[i0 * TOKENS + pos] = t;
        gate[i0 * TOKENS + pos] = p0;
        pos = atomicAdd(&count[i1], 1);
        token_id[i1 * TOKENS + pos] = t;
        gate[i1 * TOKENS + pos] = p1;
    }
}

__global__ void prefix_kernel(const int* __restrict__ count, int* __restrict__ offsets) {
    if (threadIdx.x == 0 && blockIdx.x == 0) {
        int acc = 0;
        for (int e = 0; e < NEXP; ++e) { offsets[e] = acc; acc += count[e]; }
        offsets[NEXP] = acc;
    }
}

// ---------------- f32 -> bf16 bulk convert (memory-bound) ----------------
__global__ void cvt_kernel(const float* __restrict__ src, ushort_t* __restrict__ dst, int n8) {
    int i = blockIdx.x * blockDim.x + threadIdx.x;
    if (i >= n8) return;
    const float4* s = (const float4*)(src + (size_t)i * 8);
    float4 a = s[0], b = s[1];
    ushort_t o[8];
    o[0] = f2b(a.x); o[1] = f2b(a.y); o[2] = f2b(a.z); o[3] = f2b(a.w);
    o[4] = f2b(b.x); o[5] = f2b(b.y); o[6] = f2b(b.z); o[7] = f2b(b.w);
    *(short8*)(dst + (size_t)i * 8) = *(short8*)o;
}

// Pipelined 2-phase K-loop (T3 minimal recipe): double-buffered LDS,
// next-tile global_load_lds issued BEFORE current-tile compute, counted
// vmcnt(4) so prefetch loads stay in flight across the raw s_barrier.
// Rationale: gemm2 measured latency-bound (MfmaUtil 18%, occ 19-24%,
// VALU 8%) -- serial vmcnt(0)-at-barrier exposed full load latency/iter.

// ---------------- GEMM1: h[row] = gelu(xb[tok] . W1b[e]^T), bf16 out ----------------
__global__ __launch_bounds__(256) void gemm1_kernel(
        const ushort_t* __restrict__ xb, const ushort_t* __restrict__ W1b,
        const int* __restrict__ count, const int* __restrict__ offsets,
        const int* __restrict__ token_id, ushort_t* __restrict__ h) {
    const int e = blockIdx.z;
    const int cnt = count[e];
    const int mt = blockIdx.y;
    if (mt * 128 >= cnt) return;
    const int nt = blockIdx.x;
    const int base = offsets[e];

    __shared__ __align__(16) ushort_t As[2][128 * 32];
    __shared__ __align__(16) ushort_t Bs[2][128 * 32];

    const int tid = threadIdx.x;
    const int lane = tid & 63;
    const int wave = tid >> 6;

    // staging geometry: wave w stages rows [w*32, w*32+32), 2 loads of 16 rows.
    const int sr0 = (wave << 5) + (lane >> 2);
    const int sr1 = sr0 + 16;
    const int sc  = (lane & 3) << 3;

    int ra0 = mt * 128 + sr0; if (ra0 >= cnt) ra0 = cnt - 1;   // clamp: garbage rows unused
    int ra1 = mt * 128 + sr1; if (ra1 >= cnt) ra1 = cnt - 1;
    const int t0 = token_id[e * TOKENS + ra0];
    const int t1 = token_id[e * TOKENS + ra1];
    const ushort_t* pa0 = xb + (size_t)t0 * H_DIM + sc;
    const ushort_t* pa1 = xb + (size_t)t1 * H_DIM + sc;
    const ushort_t* pb0 = W1b + (size_t)e * HFF_DIM * H_DIM
                          + (size_t)(nt * 128 + sr0) * H_DIM + sc;
    const ushort_t* pb1 = pb0 + (size_t)16 * H_DIM;
    const int lbase = wave << 10;

    const int wm = (wave >> 1) << 6;
    const int wn = (wave & 1) << 6;
    const int lr = lane & 15;
    const int lq = lane >> 4;

    f32x4 acc[4][4];
#pragma unroll
    for (int mi = 0; mi < 4; ++mi)
#pragma unroll
        for (int ni = 0; ni < 4; ++ni)
            acc[mi][ni] = (f32x4){0.f, 0.f, 0.f, 0.f};

#define STAGE1(buf, k0) do { \
    gload16(pa0 + (k0), &As[buf][lbase]);       \
    gload16(pa1 + (k0), &As[buf][lbase + 512]); \
    gload16(pb0 + (k0), &Bs[buf][lbase]);       \
    gload16(pb1 + (k0), &Bs[buf][lbase + 512]); \
} while (0)

#define COMPUTE1(buf) do { \
    short8 af[4], bf[4]; \
    _Pragma("unroll") \
    for (int mi = 0; mi < 4; ++mi) \
        af[mi] = *(const short8*)&As[buf][(wm + mi * 16 + lr) * 32 + lq * 8]; \
    _Pragma("unroll") \
    for (int ni = 0; ni < 4; ++ni) \
        bf[ni] = *(const short8*)&Bs[buf][(wn + ni * 16 + lr) * 32 + lq * 8]; \
    _Pragma("unroll") \
    for (int mi = 0; mi < 4; ++mi) \
        _Pragma("unroll") \
        for (int ni = 0; ni < 4; ++ni) \
            acc[mi][ni] = __builtin_amdgcn_mfma_f32_16x16x32_bf16( \
                af[mi], bf[ni], acc[mi][ni], 0, 0, 0); \
} while (0)

    const int NT1 = H_DIM / 32;
    STAGE1(0, 0);
    int cur = 0;
#pragma unroll 2
    for (int t = 0; t < NT1 - 1; ++t) {
        STAGE1(cur ^ 1, (t + 1) * 32);                 // prefetch next tile
        asm volatile("s_waitcnt vmcnt(4)" ::: "memory"); // tile t's 4 loads done; next 4 in flight
        __builtin_amdgcn_s_barrier();                  // all waves' tile-t loads landed
        COMPUTE1(cur);
        __builtin_amdgcn_s_barrier();                  // reads done before next overwrite
        cur ^= 1;
    }
    asm volatile("s_waitcnt vmcnt(0)" ::: "memory");
    __builtin_amdgcn_s_barrier();
    COMPUTE1(cur);

    // epilogue: gelu -> bf16 h
#pragma unroll
    for (int mi = 0; mi < 4; ++mi) {
#pragma unroll
        for (int r = 0; r < 4; ++r) {
            int m = mt * 128 + wm + mi * 16 + lq * 4 + r;
            if (m < cnt) {
                ushort_t* hp = h + (size_t)(base + m) * HFF_DIM + nt * 128 + wn + lr;
#pragma unroll
                for (int ni = 0; ni < 4; ++ni)
                    hp[ni * 16] = f2b(gelu_tanh(acc[mi][ni][r]));
            }
        }
    }
#undef STAGE1
#undef COMPUTE1
}

// ---------------- GEMM2: out[tok] += gate * (h[row] . W2b[e]^T) ----------------
__global__ __launch_bounds__(256) void gemm2_kernel(
        const ushort_t* __restrict__ h, const ushort_t* __restrict__ W2b,
        const int* __restrict__ count, const int* __restrict__ offsets,
        const int* __restrict__ token_id, const float* __restrict__ gate,
        float* __restrict__ out) {
    const int e = blockIdx.z;
    const int cnt = count[e];
    const int mt = blockIdx.y;
    if (mt * 128 >= cnt) return;
    const int nt = blockIdx.x;
    const int base = offsets[e];

    __shared__ __align__(16) ushort_t As[2][128 * 32];
    __shared__ __align__(16) ushort_t Bs[2][128 * 32];

    const int tid = threadIdx.x;
    const int lane = tid & 63;
    const int wave = tid >> 6;

    const int sr0 = (wave << 5) + (lane >> 2);
    const int sr1 = sr0 + 16;
    const int sc  = (lane & 3) << 3;

    int ra0 = mt * 128 + sr0; if (ra0 >= cnt) ra0 = cnt - 1;
    int ra1 = mt * 128 + sr1; if (ra1 >= cnt) ra1 = cnt - 1;
    const ushort_t* pa0 = h + (size_t)(base + ra0) * HFF_DIM + sc;
    const ushort_t* pa1 = h + (size_t)(base + ra1) * HFF_DIM + sc;
    const ushort_t* pb0 = W2b + (size_t)e * H_DIM * HFF_DIM
                          + (size_t)(nt * 128 + sr0) * HFF_DIM + sc;
    const ushort_t* pb1 = pb0 + (size_t)16 * HFF_DIM;
    const int lbase = wave << 10;

    const int wm = (wave >> 1) << 6;
    const int wn = (wave & 1) << 6;
    const int lr = lane & 15;
    const int lq = lane >> 4;

    f32x4 acc[4][4];
#pragma unroll
    for (int mi = 0; mi < 4; ++mi)
#pragma unroll
        for (int ni = 0; ni < 4; ++ni)
            acc[mi][ni] = (f32x4){0.f, 0.f, 0.f, 0.f};

#define STAGE2(buf, k0) do { \
    gload16(pa0 + (k0), &As[buf][lbase]);       \
    gload16(pa1 + (k0), &As[buf][lbase + 512]); \
    gload16(pb0 + (k0), &Bs[buf][lbase]);       \
    gload16(pb1 + (k0), &Bs[buf][lbase + 512]); \
} while (0)

#define COMPUTE2(buf) do { \
    short8 af[4], bf[4]; \
    _Pragma("unroll") \
    for (int mi = 0; mi < 4; ++mi) \
        af[mi] = *(const short8*)&As[buf][(wm + mi * 16 + lr) * 32 + lq * 8]; \
    _Pragma("unroll") \
    for (int ni = 0; ni < 4; ++ni) \
        bf[ni] = *(const short8*)&Bs[buf][(wn + ni * 16 + lr) * 32 + lq * 8]; \
    _Pragma("unroll") \
    for (int mi = 0; mi < 4; ++mi) \
        _Pragma("unroll") \
        for (int ni = 0; ni < 4; ++ni) \
            acc[mi][ni] = __builtin_amdgcn_mfma_f32_16x16x32_bf16( \
                af[mi], bf[ni], acc[mi][ni], 0, 0, 0); \
} while (0)

    const int NT2 = HFF_DIM / 32;
    STAGE2(0, 0);
    int cur = 0;
#pragma unroll 2
    for (int t = 0; t < NT2 - 1; ++t) {
        STAGE2(cur ^ 1, (t + 1) * 32);
        asm volatile("s_waitcnt vmcnt(4)" ::: "memory");
        __builtin_amdgcn_s_barrier();
        COMPUTE2(cur);
        __builtin_amdgcn_s_barrier();
        cur ^= 1;
    }
    asm volatile("s_waitcnt vmcnt(0)" ::: "memory");
    __builtin_amdgcn_s_barrier();
    COMPUTE2(cur);

    // epilogue: scale by gate, scatter-add into out
#pragma unroll
    for (int mi = 0; mi < 4; ++mi) {
#pragma unroll
        for (int r = 0; r < 4; ++r) {
            int m = mt * 128 + wm + mi * 16 + lq * 4 + r;
            if (m < cnt) {
                int tok = token_id[e * TOKENS + m];
                float g = gate[e * TOKENS + m];
                float* op = out + (size_t)tok * H_DIM + nt * 128 + wn + lr;
#pragma unroll
                for (int ni = 0; ni < 4; ++ni)
                    atomicAdd(&op[ni * 16], g * acc[mi][ni][r]);
            }
        }
    }
#undef STAGE2
#undef COMPUTE2
}

extern "C" void kernel_launch(void* const* d_in, const int* in_sizes, int n_in,
                              void* d_out, int out_size, void* d_ws, size_t ws_size,
                              hipStream_t stream) {
    const float* x     = (const float*)d_in[0];
    const float* probs = (const float*)d_in[1];
    const int*   idx   = (const int*)d_in[2];
    const float* W1    = (const float*)d_in[3];
    const float* W2    = (const float*)d_in[4];
    float* out = (float*)d_out;

    char* ws = (char*)d_ws;
    int*      count    = (int*)ws;                               // 8 ints
    int*      offsets  = (int*)(ws + 64);                        // 9 ints
    int*      token_id = (int*)(ws + 4096);                      // 8*4096 ints (128 KB)
    float*    gate     = (float*)(ws + 4096 + 8 * TOKENS * 4);   // 128 KB
    ushort_t* xb       = (ushort_t*)(ws + ((size_t)1 << 20));              // 8 MB bf16 x
    ushort_t* Wb       = (ushort_t*)(ws + ((size_t)1 << 20) + ((size_t)8 << 20));   // 64 MB (W1b then W2b)
    ushort_t* h        = (ushort_t*)(ws + ((size_t)1 << 20) + ((size_t)72 << 20));  // 64 MB
    // total workspace footprint ~137 MB

    hipMemsetAsync(count, 0, 64, stream);
    hipMemsetAsync(out, 0, (size_t)out_size * sizeof(float), stream);

    route_kernel<<<TOKENS / 256, 256, 0, stream>>>(probs, idx, count, token_id, gate);
    prefix_kernel<<<1, 64, 0, stream>>>(count, offsets);

    // bf16 pre-conversion (once per launch, memory-bound)
    {
        int n8 = TOKENS * H_DIM / 8;
        cvt_kernel<<<(n8 + 255) / 256, 256, 0, stream>>>(x, xb, n8);
    }
    {
        int n8 = NEXP * HFF_DIM * H_DIM / 8;
        cvt_kernel<<<(n8 + 255) / 256, 256, 0, stream>>>(W1, Wb, n8);
    }

    dim3 g1(HFF_DIM / 128, TOKENS / 128, NEXP);
    gemm1_kernel<<<g1, 256, 0, stream>>>(xb, Wb, count, offsets, token_id, h);

    // convert W2 into the same buffer (stream-ordered after gemm1 reads W1b)
    {
        int n8 = NEXP * H_DIM * HFF_DIM / 8;
        cvt_kernel<<<(n8 + 255) / 256, 256, 0, stream>>>(W2, Wb, n8);
    }

    dim3 g2(H_DIM / 128, TOKENS / 128, NEXP);
    gemm2_kernel<<<g2, 256, 0, stream>>>(h, Wb, count, offsets, token_id, gate, out);
}

// Round 8
// 560.663 us; speedup vs baseline: 1.0836x; 1.0836x over previous
//
#include <hip/hip_runtime.h>

typedef unsigned short ushort_t;
typedef __attribute__((ext_vector_type(8))) short short8;
typedef __attribute__((ext_vector_type(4))) float f32x4;

#define TOKENS  4096
#define H_DIM   1024
#define HFF_DIM 4096
#define NEXP    8

// round-to-nearest-even f32 -> bf16
__device__ __forceinline__ ushort_t f2b(float f) {
    union { float f; unsigned u; } v; v.f = f;
    unsigned r = v.u + 0x7fffu + ((v.u >> 16) & 1u);
    return (ushort_t)(r >> 16);
}

// jax.nn.gelu default: approximate=True (tanh form)
__device__ __forceinline__ float gelu_tanh(float x) {
    float u = 0.7978845608028654f * (x + 0.044715f * x * x * x);
    return 0.5f * x * (1.0f + tanhf(u));
}

// async global->LDS, 16B per lane; LDS dest is wave-uniform base + lane*16
__device__ __forceinline__ void gload16(const ushort_t* g, ushort_t* l) {
    __builtin_amdgcn_global_load_lds(
        (const __attribute__((address_space(1))) unsigned int*)g,
        (__attribute__((address_space(3))) unsigned int*)l,
        16, 0, 0);
}

// ---------------- routing ----------------
__global__ void route_kernel(const float* __restrict__ probs,
                             const int* __restrict__ idx,
                             int* __restrict__ count,
                             int* __restrict__ token_id,
                             float* __restrict__ gate) {
    int t = blockIdx.x * blockDim.x + threadIdx.x;
    if (t >= TOKENS) return;
    int i0 = idx[t * 2 + 0];
    int i1 = idx[t * 2 + 1];
    float p0 = probs[t * 2 + 0];
    float p1 = probs[t * 2 + 1];
    if (i0 == i1) {
        float p = fmaxf(p0, p1);
        int pos = atomicAdd(&count[i0], 1);
        token_id[i0 * TOKENS + pos] = t;
        gate[i0 * TOKENS + pos] = p;
    } else {
        int pos = atomicAdd(&count[i0], 1);
        token_id[i0 * TOKENS + pos] = t;
        gate[i0 * TOKENS + pos] = p0;
        pos = atomicAdd(&count[i1], 1);
        token_id[i1 * TOKENS + pos] = t;
        gate[i1 * TOKENS + pos] = p1;
    }
}

__global__ void prefix_kernel(const int* __restrict__ count, int* __restrict__ offsets) {
    if (threadIdx.x == 0 && blockIdx.x == 0) {
        int acc = 0;
        for (int e = 0; e < NEXP; ++e) { offsets[e] = acc; acc += count[e]; }
        offsets[NEXP] = acc;
    }
}

// ---------------- f32 -> bf16 bulk convert (memory-bound) ----------------
__global__ void cvt_kernel(const float* __restrict__ src, ushort_t* __restrict__ dst, int n8) {
    int i = blockIdx.x * blockDim.x + threadIdx.x;
    if (i >= n8) return;
    const float4* s = (const float4*)(src + (size_t)i * 8);
    float4 a = s[0], b = s[1];
    ushort_t o[8];
    o[0] = f2b(a.x); o[1] = f2b(a.y); o[2] = f2b(a.z); o[3] = f2b(a.w);
    o[4] = f2b(b.x); o[5] = f2b(b.y); o[6] = f2b(b.z); o[7] = f2b(b.w);
    *(short8*)(dst + (size_t)i * 8) = *(short8*)o;
}

// ---------------- GEMM1: h[row] = gelu(xb[tok] . W1b[e]^T), bf16 out ----------------
// R5-verified m97 structure (best measured). 1D grid + XCD-chunked swizzle (T1):
// consecutive work-items (same mt, adjacent nt -> shared A-panel) land on ONE
// XCD's L2 instead of 8 different ones. nwg = 8*32*32 = 8192, /8 = 1024 = one
// expert per XCD -> W1b panel locality too.
__global__ __launch_bounds__(256) void gemm1_kernel(
        const ushort_t* __restrict__ xb, const ushort_t* __restrict__ W1b,
        const int* __restrict__ count, const int* __restrict__ offsets,
        const int* __restrict__ token_id, ushort_t* __restrict__ h) {
    const int wg  = blockIdx.x;
    const int swz = (wg & 7) * (NEXP * 32 * 32 / 8) + (wg >> 3);
    const int e   = swz >> 10;          // 32 mt * 32 nt = 1024 per expert
    const int rem = swz & 1023;
    const int mt  = rem >> 5;           // nt fastest: A-panel sharers consecutive
    const int nt  = rem & 31;

    const int cnt = count[e];
    if (mt * 128 >= cnt) return;
    const int base = offsets[e];

    __shared__ __align__(16) ushort_t As[128 * 32];
    __shared__ __align__(16) ushort_t Bs[128 * 32];

    const int tid = threadIdx.x;
    const int lane = tid & 63;
    const int wave = tid >> 6;

    // staging geometry: wave w stages rows [w*32, w*32+32), 2 loads of 16 rows.
    const int sr0 = (wave << 5) + (lane >> 2);
    const int sr1 = sr0 + 16;
    const int sc  = (lane & 3) << 3;

    int ra0 = mt * 128 + sr0; if (ra0 >= cnt) ra0 = cnt - 1;   // clamp: garbage rows unused
    int ra1 = mt * 128 + sr1; if (ra1 >= cnt) ra1 = cnt - 1;
    const int t0 = token_id[e * TOKENS + ra0];
    const int t1 = token_id[e * TOKENS + ra1];
    const ushort_t* pa0 = xb + (size_t)t0 * H_DIM + sc;
    const ushort_t* pa1 = xb + (size_t)t1 * H_DIM + sc;
    const ushort_t* pb0 = W1b + (size_t)e * HFF_DIM * H_DIM
                          + (size_t)(nt * 128 + sr0) * H_DIM + sc;
    const ushort_t* pb1 = pb0 + (size_t)16 * H_DIM;
    ushort_t* lA0 = &As[wave << 10];
    ushort_t* lA1 = lA0 + 512;
    ushort_t* lB0 = &Bs[wave << 10];
    ushort_t* lB1 = lB0 + 512;

    const int wm = (wave >> 1) << 6;
    const int wn = (wave & 1) << 6;
    const int lr = lane & 15;
    const int lq = lane >> 4;

    f32x4 acc[4][4];
#pragma unroll
    for (int mi = 0; mi < 4; ++mi)
#pragma unroll
        for (int ni = 0; ni < 4; ++ni)
            acc[mi][ni] = (f32x4){0.f, 0.f, 0.f, 0.f};

    for (int k0 = 0; k0 < H_DIM; k0 += 32) {
        __syncthreads();                 // prior ds_reads done before overwrite
        gload16(pa0 + k0, lA0);
        gload16(pa1 + k0, lA1);
        gload16(pb0 + k0, lB0);
        gload16(pb1 + k0, lB1);
        __syncthreads();                 // loads landed (vmcnt drained at barrier)

        short8 af[4], bf[4];
#pragma unroll
        for (int mi = 0; mi < 4; ++mi)
            af[mi] = *(const short8*)&As[(wm + mi * 16 + lr) * 32 + lq * 8];
#pragma unroll
        for (int ni = 0; ni < 4; ++ni)
            bf[ni] = *(const short8*)&Bs[(wn + ni * 16 + lr) * 32 + lq * 8];
#pragma unroll
        for (int mi = 0; mi < 4; ++mi)
#pragma unroll
            for (int ni = 0; ni < 4; ++ni)
                acc[mi][ni] = __builtin_amdgcn_mfma_f32_16x16x32_bf16(
                    af[mi], bf[ni], acc[mi][ni], 0, 0, 0);
    }

    // epilogue: gelu -> bf16 h
#pragma unroll
    for (int mi = 0; mi < 4; ++mi) {
#pragma unroll
        for (int r = 0; r < 4; ++r) {
            int m = mt * 128 + wm + mi * 16 + lq * 4 + r;
            if (m < cnt) {
                ushort_t* hp = h + (size_t)(base + m) * HFF_DIM + nt * 128 + wn + lr;
#pragma unroll
                for (int ni = 0; ni < 4; ++ni)
                    hp[ni * 16] = f2b(gelu_tanh(acc[mi][ni][r]));
            }
        }
    }
}

// ---------------- GEMM2: out[tok] += gate * (h[row] . W2b[e]^T) ----------------
// R5-verified structure + XCD-chunked swizzle. nwg = 8*32*8 = 2048, /8 = 256
// per XCD = one expert per XCD.
__global__ __launch_bounds__(256) void gemm2_kernel(
        const ushort_t* __restrict__ h, const ushort_t* __restrict__ W2b,
        const int* __restrict__ count, const int* __restrict__ offsets,
        const int* __restrict__ token_id, const float* __restrict__ gate,
        float* __restrict__ out) {
    const int wg  = blockIdx.x;
    const int swz = (wg & 7) * (NEXP * 32 * 8 / 8) + (wg >> 3);
    const int e   = swz >> 8;           // 32 mt * 8 nt = 256 per expert
    const int rem = swz & 255;
    const int mt  = rem >> 3;
    const int nt  = rem & 7;

    const int cnt = count[e];
    if (mt * 128 >= cnt) return;
    const int base = offsets[e];

    __shared__ __align__(16) ushort_t As[128 * 32];
    __shared__ __align__(16) ushort_t Bs[128 * 32];

    const int tid = threadIdx.x;
    const int lane = tid & 63;
    const int wave = tid >> 6;

    const int sr0 = (wave << 5) + (lane >> 2);
    const int sr1 = sr0 + 16;
    const int sc  = (lane & 3) << 3;

    int ra0 = mt * 128 + sr0; if (ra0 >= cnt) ra0 = cnt - 1;
    int ra1 = mt * 128 + sr1; if (ra1 >= cnt) ra1 = cnt - 1;
    const ushort_t* pa0 = h + (size_t)(base + ra0) * HFF_DIM + sc;
    const ushort_t* pa1 = h + (size_t)(base + ra1) * HFF_DIM + sc;
    const ushort_t* pb0 = W2b + (size_t)e * H_DIM * HFF_DIM
                          + (size_t)(nt * 128 + sr0) * HFF_DIM + sc;
    const ushort_t* pb1 = pb0 + (size_t)16 * HFF_DIM;
    ushort_t* lA0 = &As[wave << 10];
    ushort_t* lA1 = lA0 + 512;
    ushort_t* lB0 = &Bs[wave << 10];
    ushort_t* lB1 = lB0 + 512;

    const int wm = (wave >> 1) << 6;
    const int wn = (wave & 1) << 6;
    const int lr = lane & 15;
    const int lq = lane >> 4;

    f32x4 acc[4][4];
#pragma unroll
    for (int mi = 0; mi < 4; ++mi)
#pragma unroll
        for (int ni = 0; ni < 4; ++ni)
            acc[mi][ni] = (f32x4){0.f, 0.f, 0.f, 0.f};

    for (int k0 = 0; k0 < HFF_DIM; k0 += 32) {
        __syncthreads();
        gload16(pa0 + k0, lA0);
        gload16(pa1 + k0, lA1);
        gload16(pb0 + k0, lB0);
        gload16(pb1 + k0, lB1);
        __syncthreads();

        short8 af[4], bf[4];
#pragma unroll
        for (int mi = 0; mi < 4; ++mi)
            af[mi] = *(const short8*)&As[(wm + mi * 16 + lr) * 32 + lq * 8];
#pragma unroll
        for (int ni = 0; ni < 4; ++ni)
            bf[ni] = *(const short8*)&Bs[(wn + ni * 16 + lr) * 32 + lq * 8];
#pragma unroll
        for (int mi = 0; mi < 4; ++mi)
#pragma unroll
            for (int ni = 0; ni < 4; ++ni)
                acc[mi][ni] = __builtin_amdgcn_mfma_f32_16x16x32_bf16(
                    af[mi], bf[ni], acc[mi][ni], 0, 0, 0);
    }

    // epilogue: scale by gate, scatter-add into out
#pragma unroll
    for (int mi = 0; mi < 4; ++mi) {
#pragma unroll
        for (int r = 0; r < 4; ++r) {
            int m = mt * 128 + wm + mi * 16 + lq * 4 + r;
            if (m < cnt) {
                int tok = token_id[e * TOKENS + m];
                float g = gate[e * TOKENS + m];
                float* op = out + (size_t)tok * H_DIM + nt * 128 + wn + lr;
#pragma unroll
                for (int ni = 0; ni < 4; ++ni)
                    atomicAdd(&op[ni * 16], g * acc[mi][ni][r]);
            }
        }
    }
}

extern "C" void kernel_launch(void* const* d_in, const int* in_sizes, int n_in,
                              void* d_out, int out_size, void* d_ws, size_t ws_size,
                              hipStream_t stream) {
    const float* x     = (const float*)d_in[0];
    const float* probs = (const float*)d_in[1];
    const int*   idx   = (const int*)d_in[2];
    const float* W1    = (const float*)d_in[3];
    const float* W2    = (const float*)d_in[4];
    float* out = (float*)d_out;

    char* ws = (char*)d_ws;
    int*      count    = (int*)ws;                               // 8 ints
    int*      offsets  = (int*)(ws + 64);                        // 9 ints
    int*      token_id = (int*)(ws + 4096);                      // 8*4096 ints (128 KB)
    float*    gate     = (float*)(ws + 4096 + 8 * TOKENS * 4);   // 128 KB
    ushort_t* xb       = (ushort_t*)(ws + ((size_t)1 << 20));              // 8 MB bf16 x
    ushort_t* Wb       = (ushort_t*)(ws + ((size_t)1 << 20) + ((size_t)8 << 20));   // 64 MB (W1b then W2b)
    ushort_t* h        = (ushort_t*)(ws + ((size_t)1 << 20) + ((size_t)72 << 20));  // 64 MB
    // total workspace footprint ~137 MB

    hipMemsetAsync(count, 0, 64, stream);
    hipMemsetAsync(out, 0, (size_t)out_size * sizeof(float), stream);

    route_kernel<<<TOKENS / 256, 256, 0, stream>>>(probs, idx, count, token_id, gate);
    prefix_kernel<<<1, 64, 0, stream>>>(count, offsets);

    // bf16 pre-conversion (once per launch, memory-bound)
    {
        int n8 = TOKENS * H_DIM / 8;
        cvt_kernel<<<(n8 + 255) / 256, 256, 0, stream>>>(x, xb, n8);
    }
    {
        int n8 = NEXP * HFF_DIM * H_DIM / 8;
        cvt_kernel<<<(n8 + 255) / 256, 256, 0, stream>>>(W1, Wb, n8);
    }

    gemm1_kernel<<<NEXP * 32 * 32, 256, 0, stream>>>(xb, Wb, count, offsets, token_id, h);

    // convert W2 into the same buffer (stream-ordered after gemm1 reads W1b)
    {
        int n8 = NEXP * H_DIM * HFF_DIM / 8;
        cvt_kernel<<<(n8 + 255) / 256, 256, 0, stream>>>(W2, Wb, n8);
    }

    gemm2_kernel<<<NEXP * 32 * 8, 256, 0, stream>>>(h, Wb, count, offsets, token_id, gate, out);
}